// Round 1
// baseline (348.370 us; speedup 1.0000x reference)
//
#include <hip/hip_runtime.h>

#define N_SEQ 256
#define T_LEN 1024
#define TP1   (T_LEN + 1)          // 1025
#define J_NUM 24
#define ITEMS (TP1 * J_NUM)        // 24600 items per sequence
#define GP_TOTAL (N_SEQ * TP1 * J_NUM * 3)   // global_pos element count

// Inclusive block scan over 1024 threads (16 waves of 64). wsum must be a
// distinct 16-float LDS buffer per call site (calls are internally barriered).
__device__ __forceinline__ float block_scan_incl(float v, float* wsum, int tid) {
    const int lane = tid & 63;
    const int wid  = tid >> 6;
    #pragma unroll
    for (int off = 1; off < 64; off <<= 1) {
        float u = __shfl_up(v, off, 64);
        if (lane >= off) v += u;
    }
    if (lane == 63) wsum[wid] = v;
    __syncthreads();
    if (tid == 0) {
        float acc = 0.0f;
        #pragma unroll
        for (int i = 0; i < 16; ++i) { float t = wsum[i]; wsum[i] = acc; acc += t; }
    }
    __syncthreads();
    return v + wsum[wid];
}

extern "C" __global__ void __launch_bounds__(1024)
unprocess_kernel(const float* __restrict__ root_rvel,   // (N, T, 1, 1)
                 const float* __restrict__ local_pos,   // (N, T+1, J, 3)
                 const float* __restrict__ local_rot,   // (N, T+1, J, 6)
                 const float* __restrict__ root_vel,    // (N, T, 1, 2)
                 float* __restrict__ out_pos,           // (N, T+1, J, 3)
                 float* __restrict__ out_rot)           // (N, T+1, J, 4)
{
    const int n   = blockIdx.x;
    const int tid = threadIdx.x;

    __shared__ float  r_s[TP1];      // cumulated yaw angle, r_s[0] = 0
    __shared__ float2 quat_s[TP1];   // yaw quaternion (w, y); x = z = 0 always
    __shared__ float2 pos_s[TP1];    // root displacement (x, z); y = 0 exactly
    __shared__ float  ws_a[16], ws_b[16], ws_c[16];

    // ---- Phase 1a: scan root_rvel over T -> r ----
    {
        float v = root_rvel[n * T_LEN + tid];
        float incl = block_scan_incl(v, ws_a, tid);
        if (tid == 0) r_s[0] = 0.0f;
        r_s[tid + 1] = incl;
    }
    __syncthreads();

    // ---- Phase 1b: axis-angle (0, r, 0) -> quaternion (w, 0, y, 0) ----
    for (int idx = tid; idx < TP1; idx += 1024) {
        float r     = r_s[idx];
        float angle = fabsf(r);
        float half  = 0.5f * angle;
        float k = (angle < 1e-6f) ? (0.5f - angle * angle * (1.0f / 48.0f))
                                  : (__builtin_sinf(half) / angle);
        quat_s[idx] = make_float2(__builtin_cosf(half), r * k);
    }
    __syncthreads();

    // ---- Phase 1c: rotate root_vel by quat[t], scan over T -> pos_xz ----
    {
        float2 vel = ((const float2*)root_vel)[n * T_LEN + tid];  // (vx, vz)
        float2 q   = quat_s[tid];
        float  w = q.x, y = q.y;
        // quat_apply((w,0,y,0), (vx,0,vz)); y component is exactly 0.
        float t1x = w * vel.x + y * vel.y;
        float t1z = w * vel.y - y * vel.x;
        float ax  = t1x * w + t1z * y;
        float az  = t1z * w - t1x * y;
        float ix = block_scan_incl(ax, ws_b, tid);
        float iz = block_scan_incl(az, ws_c, tid);
        if (tid == 0) pos_s[0] = make_float2(0.0f, 0.0f);
        pos_s[tid + 1] = make_float2(ix, iz);
    }
    __syncthreads();

    // ---- Phase 2: per (t, j) item ----
    const long long item_base = (long long)n * ITEMS;
    for (int idx = tid; idx < ITEMS; idx += 1024) {
        const int t = idx / J_NUM;
        const long long item = item_base + idx;

        // --- 6D rotation -> local quaternion ---
        const float* rp = local_rot + item * 6;   // 8-byte aligned (24B stride)
        float2 d01 = *(const float2*)(rp + 0);
        float2 d23 = *(const float2*)(rp + 2);
        float2 d45 = *(const float2*)(rp + 4);
        float a1x = d01.x, a1y = d01.y, a1z = d23.x;
        float a2x = d23.y, a2y = d45.x, a2z = d45.y;

        float inv1 = 1.0f / sqrtf(a1x * a1x + a1y * a1y + a1z * a1z);
        float b1x = a1x * inv1, b1y = a1y * inv1, b1z = a1z * inv1;
        float dp  = b1x * a2x + b1y * a2y + b1z * a2z;
        float px  = a2x - dp * b1x, py = a2y - dp * b1y, pz = a2z - dp * b1z;
        float inv2 = 1.0f / sqrtf(px * px + py * py + pz * pz);
        float b2x = px * inv2, b2y = py * inv2, b2z = pz * inv2;
        float b3x = b1y * b2z - b1z * b2y;
        float b3y = b1z * b2x - b1x * b2z;
        float b3z = b1x * b2y - b1y * b2x;
        // M rows = b1, b2, b3
        float m00 = b1x, m01 = b1y, m02 = b1z;
        float m10 = b2x, m11 = b2y, m12 = b2z;
        float m20 = b3x, m21 = b3y, m22 = b3z;

        float qa0 = sqrtf(fmaxf(1.0f + m00 + m11 + m22, 0.0f));
        float qa1 = sqrtf(fmaxf(1.0f + m00 - m11 - m22, 0.0f));
        float qa2 = sqrtf(fmaxf(1.0f - m00 + m11 - m22, 0.0f));
        float qa3 = sqrtf(fmaxf(1.0f - m00 - m11 + m22, 0.0f));

        int best = 0; float bv = qa0;
        if (qa1 > bv) { best = 1; bv = qa1; }
        if (qa2 > bv) { best = 2; bv = qa2; }
        if (qa3 > bv) { best = 3; bv = qa3; }

        float lw, lx, ly, lz;
        if (best == 0)      { lw = qa0 * qa0;  lx = m21 - m12;  ly = m02 - m20;  lz = m10 - m01; }
        else if (best == 1) { lw = m21 - m12;  lx = qa1 * qa1;  ly = m10 + m01;  lz = m02 + m20; }
        else if (best == 2) { lw = m02 - m20;  lx = m10 + m01;  ly = qa2 * qa2;  lz = m21 + m12; }
        else                { lw = m10 - m01;  lx = m20 + m02;  ly = m21 + m12;  lz = qa3 * qa3; }
        float invd = 1.0f / (2.0f * fmaxf(bv, 0.1f));
        lw *= invd; lx *= invd; ly *= invd; lz *= invd;

        // --- compose with yaw quat (w,0,y,0), standardize ---
        float2 qt = quat_s[t];
        float w = qt.x, yq = qt.y;
        float ow = w * lw - yq * ly;
        float ox = w * lx + yq * lz;
        float oy = w * ly + yq * lw;
        float oz = w * lz - yq * lx;
        if (ow < 0.0f) { ow = -ow; ox = -ox; oy = -oy; oz = -oz; }
        *(float4*)(out_rot + item * 4) = make_float4(ow, ox, oy, oz);

        // --- rotate local_pos, add root displacement ---
        const float* pp = local_pos + item * 3;
        float vx = pp[0], vy = pp[1], vz = pp[2];
        float t1x = w * vx + yq * vz;
        float t1z = w * vz - yq * vx;
        float rx = t1x * w + t1z * yq;
        float ry = (w * w + yq * yq) * vy;
        float rz = t1z * w - t1x * yq;
        float2 ps = pos_s[t];
        out_pos[item * 3 + 0] = rx + ps.x;
        out_pos[item * 3 + 1] = ry;
        out_pos[item * 3 + 2] = rz + ps.y;
    }
}

extern "C" void kernel_launch(void* const* d_in, const int* in_sizes, int n_in,
                              void* d_out, int out_size, void* d_ws, size_t ws_size,
                              hipStream_t stream) {
    (void)in_sizes; (void)n_in; (void)d_ws; (void)ws_size; (void)out_size;
    const float* root_rvel = (const float*)d_in[0];
    const float* local_pos = (const float*)d_in[1];
    const float* local_rot = (const float*)d_in[2];
    const float* root_vel  = (const float*)d_in[3];
    float* out = (float*)d_out;
    unprocess_kernel<<<N_SEQ, 1024, 0, stream>>>(
        root_rvel, local_pos, local_rot, root_vel, out, out + GP_TOTAL);
}